// Round 1
// baseline (2128.728 us; speedup 1.0000x reference)
//
#include <hip/hip_runtime.h>
#include <stdint.h>

// ---------------------------------------------------------------------------
// DeepSeek-V2 decoder layer, MI355X round 0.
// Strategy: bf16 MFMA GEMMs (16x16x32), m97-style 128x128 tile w/ global_load_lds.
// Weights transposed fp32->bf16(NxK) on the fly into a reused ws region.
// Attention: per-head materialized scores + causal softmax (flash later).
// ---------------------------------------------------------------------------

#define S_   2048
#define D_   2048
#define H_   16
#define QL_  1536
#define KVL_ 512
#define DN_  128
#define DR_  64
#define DV_  128
#define I_   8192
#define SCALE_ 0.07216878364870323f   // (DN+DR)^-0.5

typedef __bf16 bf16x8 __attribute__((ext_vector_type(8)));
typedef float f32x4 __attribute__((ext_vector_type(4)));

__device__ __forceinline__ unsigned short f2bf(float f) {
  unsigned int u = __builtin_bit_cast(unsigned int, f);
  u += 0x7fffu + ((u >> 16) & 1u);           // RNE
  return (unsigned short)(u >> 16);
}
__device__ __forceinline__ float bf2f(unsigned short b) {
  unsigned int u = ((unsigned int)b) << 16;
  return __builtin_bit_cast(float, u);
}

__device__ __forceinline__ float block_sum256(float v) {
  __shared__ float red[4];
  #pragma unroll
  for (int o = 32; o; o >>= 1) v += __shfl_xor(v, o);
  __syncthreads();
  if ((threadIdx.x & 63) == 0) red[threadIdx.x >> 6] = v;
  __syncthreads();
  return red[0] + red[1] + red[2] + red[3];
}
__device__ __forceinline__ float block_max256(float v) {
  __shared__ float red[4];
  #pragma unroll
  for (int o = 32; o; o >>= 1) v = fmaxf(v, __shfl_xor(v, o));
  __syncthreads();
  if ((threadIdx.x & 63) == 0) red[threadIdx.x >> 6] = v;
  __syncthreads();
  return fmaxf(fmaxf(red[0], red[1]), fmaxf(red[2], red[3]));
}

__device__ __forceinline__ void gload_lds16(const void* g, void* l) {
  void* gn = const_cast<void*>(g);
  __builtin_amdgcn_global_load_lds(
      (__attribute__((address_space(1))) void*)gn,
      (__attribute__((address_space(3))) void*)l, 16, 0, 0);
}

// ---------------------------------------------------------------------------
// Generic GEMM: C[M,N] = scale * A[M,K](bf16,lda) * Bt[N,K](bf16,ldb)^T (+R)
// 128x128 block tile, 256 threads (4 waves, each 64x64 = 4x4 mfma tiles).
// Requires: M%128==0, K%32==0, element offsets 16B-aligned (lda/ldb %8==0).
// N guarded in epilogue only (staging may read past N within ws — harmless).
// ---------------------------------------------------------------------------
template <int OUT_BF16, int ADD_RES>
__global__ __launch_bounds__(256) void gemm_bt(
    const unsigned short* __restrict__ A, const unsigned short* __restrict__ Bt,
    void* __restrict__ C, const float* __restrict__ R, float scale,
    int M, int N, int K, int lda, int ldb, int ldc,
    long sA, long sB, long sC) {
  __shared__ unsigned short As[128 * 32];
  __shared__ unsigned short Bs[128 * 32];
  const int b = blockIdx.z;
  const unsigned short* Ab = A + (long)b * sA;
  const unsigned short* Bb = Bt + (long)b * sB;
  const int m0 = blockIdx.y * 128, n0 = blockIdx.x * 128;
  const int tid = threadIdx.x, w = tid >> 6, lane = tid & 63;
  const int wm = (w >> 1) * 64, wn = (w & 1) * 64;
  const int fr = lane & 15;      // m (for A) / n (for B) within 16-tile
  const int fq = lane >> 4;      // quad -> k offset = fq*8

  f32x4 acc[4][4] = {};

  for (int k0 = 0; k0 < K; k0 += 32) {
    #pragma unroll
    for (int i = 0; i < 2; ++i) {
      const int c = w * 128 + i * 64 + lane;   // 16B chunk id, 512 total
      const int row = c >> 2, q = c & 3;       // 4 chunks per 32-elem row
      gload_lds16(Ab + (long)(m0 + row) * lda + k0 + q * 8,
                  As + (w * 128 + i * 64) * 8);
      gload_lds16(Bb + (long)(n0 + row) * ldb + k0 + q * 8,
                  Bs + (w * 128 + i * 64) * 8);
    }
    __syncthreads();
    bf16x8 af[4], bfr[4];
    #pragma unroll
    for (int i = 0; i < 4; ++i)
      af[i] = *(const bf16x8*)(As + (wm + i * 16 + fr) * 32 + fq * 8);
    #pragma unroll
    for (int j = 0; j < 4; ++j)
      bfr[j] = *(const bf16x8*)(Bs + (wn + j * 16 + fr) * 32 + fq * 8);
    #pragma unroll
    for (int i = 0; i < 4; ++i)
      #pragma unroll
      for (int j = 0; j < 4; ++j)
        acc[i][j] = __builtin_amdgcn_mfma_f32_16x16x32_bf16(af[i], bfr[j],
                                                            acc[i][j], 0, 0, 0);
    __syncthreads();
  }

  const long cb = (long)b * sC;
  #pragma unroll
  for (int i = 0; i < 4; ++i) {
    const int row0 = m0 + wm + i * 16 + fq * 4;
    #pragma unroll
    for (int j = 0; j < 4; ++j) {
      const int col = n0 + wn + j * 16 + fr;
      if (col < N) {
        #pragma unroll
        for (int r = 0; r < 4; ++r) {
          const long idx = cb + (long)(row0 + r) * ldc + col;
          float v = acc[i][j][r] * scale;
          if (ADD_RES) v += R[idx];
          if (OUT_BF16) ((unsigned short*)C)[idx] = f2bf(v);
          else          ((float*)C)[idx] = v;
        }
      }
    }
  }
}

// transpose + convert: in fp32 [R,C] -> out bf16 [C,R]; R,C multiples of 32.
__global__ void transpose_f2b(const float* __restrict__ in,
                              unsigned short* __restrict__ out, int Rr, int Cc,
                              long sIn, long sOut) {
  const int b = blockIdx.z;
  in += (long)b * sIn;
  out += (long)b * sOut;
  __shared__ float t[32][33];
  const int c0 = blockIdx.x * 32, r0 = blockIdx.y * 32;
  const int tx = threadIdx.x, ty = threadIdx.y;
  #pragma unroll
  for (int i = 0; i < 4; ++i)
    t[ty + i * 8][tx] = in[(long)(r0 + ty + i * 8) * Cc + c0 + tx];
  __syncthreads();
  #pragma unroll
  for (int i = 0; i < 4; ++i)
    out[(long)(c0 + ty + i * 8) * Rr + r0 + tx] = f2bf(t[tx][ty + i * 8]);
}

// rmsnorm rows: y_bf16 = x * rsqrt(mean(x^2)+eps) * w
__global__ void rmsnorm_k(const float* __restrict__ x, const float* __restrict__ w,
                          unsigned short* __restrict__ y, int C) {
  const int row = blockIdx.x, tid = threadIdx.x;
  const float* xr = x + (long)row * C;
  float ss = 0.f;
  for (int c = tid; c < C; c += 256) { float v = xr[c]; ss += v * v; }
  ss = block_sum256(ss);
  const float rms = rsqrtf(ss / C + 1e-6f);
  for (int c = tid; c < C; c += 256)
    y[(long)row * C + c] = f2bf(xr[c] * rms * w[c]);
}

// q postprocess: split q (S,3072) into qnope bf16 (S, H*128) and roped pe into
// qf[h][s][512..575]
__global__ void q_post(const float* __restrict__ q, const float* __restrict__ cs,
                       const float* __restrict__ sn, unsigned short* __restrict__ qnope,
                       unsigned short* __restrict__ qf) {
  const int s = blockIdx.x, tid = threadIdx.x;
  const float* qr = q + (long)s * 3072;
  for (int c = tid; c < 3072; c += 256) {
    const int h = c / 192, d = c % 192;
    if (d < 128) {
      qnope[(long)s * 2048 + h * 128 + d] = f2bf(qr[c]);
    } else {
      const int j = d - 128;
      const float x = qr[c];
      const float rot = (j < 32) ? -qr[h * 192 + 128 + j + 32]
                                 :  qr[h * 192 + 128 + j - 32];
      const float v = x * cs[s * 64 + j] + rot * sn[s * 64 + j];
      qf[(long)h * (S_ * 576) + (long)s * 576 + 512 + j] = f2bf(v);
    }
  }
}

// kv postprocess: rmsnorm first 512 -> kf[:, :512] and klat^T; rope last 64.
__global__ void kv_post(const float* __restrict__ kv, const float* __restrict__ w,
                        const float* __restrict__ cs, const float* __restrict__ sn,
                        unsigned short* __restrict__ kf, unsigned short* __restrict__ klt) {
  const int s = blockIdx.x, tid = threadIdx.x;
  const float* kr = kv + (long)s * 576;
  float ss = 0.f;
  for (int c = tid; c < 512; c += 256) { float v = kr[c]; ss += v * v; }
  ss = block_sum256(ss);
  const float rms = rsqrtf(ss / 512.f + 1e-6f);
  for (int c = tid; c < 576; c += 256) {
    if (c < 512) {
      const float v = kr[c] * rms * w[c];
      const unsigned short bv = f2bf(v);
      kf[(long)s * 576 + c] = bv;
      klt[(long)c * S_ + s] = bv;
    } else {
      const int j = c - 512;
      const float x = kr[c];
      const float rot = (j < 32) ? -kr[512 + j + 32] : kr[512 + j - 32];
      kf[(long)s * 576 + c] = f2bf(x * cs[s * 64 + j] + rot * sn[s * 64 + j]);
    }
  }
}

// causal softmax: scores fp32 (S,S) row -> P bf16 (cols>row zeroed)
__global__ void softmax_causal(const float* __restrict__ sc,
                               unsigned short* __restrict__ P) {
  const int row = blockIdx.x, tid = threadIdx.x;
  const float* sr = sc + (long)row * S_;
  unsigned short* pr = P + (long)row * S_;
  const int n = row + 1;
  float mx = -1e30f;
  for (int c = tid; c < n; c += 256) mx = fmaxf(mx, sr[c]);
  mx = block_max256(mx);
  float sum = 0.f;
  for (int c = tid; c < n; c += 256) sum += __expf(sr[c] - mx);
  sum = block_sum256(sum);
  const float inv = 1.f / sum;
  for (int c = tid; c < S_; c += 256)
    pr[c] = (c < n) ? f2bf(__expf(sr[c] - mx) * inv) : (unsigned short)0;
}

// hidden = resid + attn (fp32 store); x2 = rmsnorm(hidden, w) bf16
__global__ void add_rms(const float* __restrict__ resid, const float* __restrict__ attn,
                        const float* __restrict__ w, float* __restrict__ hidden,
                        unsigned short* __restrict__ x2) {
  const int s = blockIdx.x, tid = threadIdx.x;
  float ss = 0.f;
  for (int c = tid; c < D_; c += 256) {
    const float v = resid[(long)s * D_ + c] + attn[(long)s * D_ + c];
    hidden[(long)s * D_ + c] = v;
    ss += v * v;
  }
  ss = block_sum256(ss);
  const float rms = rsqrtf(ss / D_ + 1e-6f);
  for (int c = tid; c < D_; c += 256) {
    const float v = resid[(long)s * D_ + c] + attn[(long)s * D_ + c];
    x2[(long)s * D_ + c] = f2bf(v * rms * w[c]);
  }
}

// mlp_in = silu(gu[:, :I]) * gu[:, I:]
__global__ void silu_mul(const unsigned short* __restrict__ gu,
                         unsigned short* __restrict__ out) {
  const long total = (long)S_ * I_;
  for (long i = (long)blockIdx.x * 256 + threadIdx.x; i < total;
       i += (long)gridDim.x * 256) {
    const long s = i >> 13, c = i & (I_ - 1);
    const float g = bf2f(gu[s * (2 * I_) + c]);
    const float u = bf2f(gu[s * (2 * I_) + I_ + c]);
    out[i] = f2bf(g / (1.f + __expf(-g)) * u);
  }
}

// ---------------------------------------------------------------------------
extern "C" void kernel_launch(void* const* d_in, const int* in_sizes, int n_in,
                              void* d_out, int out_size, void* d_ws, size_t ws_size,
                              hipStream_t stream) {
  const float* hs   = (const float*)d_in[0];
  const float* cs   = (const float*)d_in[1];
  const float* sn   = (const float*)d_in[2];
  const float* ln1  = (const float*)d_in[3];
  const float* qaw  = (const float*)d_in[4];
  const float* qaln = (const float*)d_in[5];
  const float* qbw  = (const float*)d_in[6];
  const float* kvaw = (const float*)d_in[7];
  const float* kvln = (const float*)d_in[8];
  const float* kcw  = (const float*)d_in[9];
  const float* vcw  = (const float*)d_in[10];
  const float* ow   = (const float*)d_in[11];
  const float* ln2  = (const float*)d_in[12];
  const float* guw  = (const float*)d_in[13];
  const float* dww  = (const float*)d_in[14];
  float* out = (float*)d_out;
  char* ws = (char*)d_ws;

  // workspace layout (bytes), carefully aliased by phase; high-water ~184MiB
  unsigned short* hbf   = (unsigned short*)(ws + 0);           // S*D bf16
  float*          qa    = (float*)(ws + 8388608);              // S*QL f32
  unsigned short* qan   = (unsigned short*)(ws + 20971520);    // S*QL bf16
  float*          q     = (float*)(ws + 27262976);             // S*3072 f32
  unsigned short* qnope = (unsigned short*)(ws + 52428800);    // S*2048 bf16
  unsigned short* qf    = (unsigned short*)(ws + 60817408);    // H*S*576 bf16
  float*          kv    = (float*)(ws + 98566144);             // S*576 f32
  unsigned short* kf    = (unsigned short*)(ws + 103284736);   // S*576 bf16
  unsigned short* klt   = (unsigned short*)(ws + 105644032);   // 512*S bf16
  // attention phase (aliases dead buffers)
  float*          sc    = (float*)(ws + 0);                    // S*S f32
  unsigned short* P     = (unsigned short*)(ws + 16777216);    // S*S bf16
  unsigned short* olat  = (unsigned short*)(ws + 25165824);    // H*S*512 bf16
  unsigned short* obf   = (unsigned short*)(ws + 60817408);    // S*2048 bf16
  float*          attn  = (float*)(ws + 69206016);             // S*D f32
  float*          hidden= (float*)(ws + 0);                    // S*D f32
  unsigned short* x2    = (unsigned short*)(ws + 16777216);    // S*D bf16
  unsigned short* gu    = (unsigned short*)(ws + 25165824);    // S*2I bf16
  unsigned short* mlp   = (unsigned short*)(ws + 92274688);    // S*I bf16
  unsigned short* wt    = (unsigned short*)(ws + 125829120);   // 67MB weight scratch
  unsigned short* wt2   = (unsigned short*)(ws + 125829120 + 2097152); // vct

  const dim3 B256(256), Bt32(32, 8);

  // 1. h = rmsnorm(hidden_states, ln1)
  rmsnorm_k<<<S_, B256, 0, stream>>>(hs, ln1, hbf, D_);
  // 2-3. q_a = h @ q_a_w
  transpose_f2b<<<dim3(QL_/32, D_/32, 1), Bt32, 0, stream>>>(qaw, wt, D_, QL_, 0, 0);
  gemm_bt<0,0><<<dim3(QL_/128, S_/128, 1), B256, 0, stream>>>(
      hbf, wt, qa, nullptr, 1.f, S_, QL_, D_, D_, D_, QL_, 0, 0, 0);
  // 4. q_a_norm
  rmsnorm_k<<<S_, B256, 0, stream>>>(qa, qaln, qan, QL_);
  // 5-6. q = qan @ q_b_w
  transpose_f2b<<<dim3(3072/32, QL_/32, 1), Bt32, 0, stream>>>(qbw, wt, QL_, 3072, 0, 0);
  gemm_bt<0,0><<<dim3(3072/128, S_/128, 1), B256, 0, stream>>>(
      qan, wt, q, nullptr, 1.f, S_, 3072, QL_, QL_, QL_, 3072, 0, 0, 0);
  // 7. split q -> qnope bf16, rope(q_pe) -> qf[...,512:]
  q_post<<<S_, B256, 0, stream>>>(q, cs, sn, qnope, qf);
  // 8-9. kv = h @ kv_a_w
  transpose_f2b<<<dim3(576/32, D_/32, 1), Bt32, 0, stream>>>(kvaw, wt, D_, 576, 0, 0);
  gemm_bt<0,0><<<dim3(5, S_/128, 1), B256, 0, stream>>>(
      hbf, wt, kv, nullptr, 1.f, S_, 576, D_, D_, D_, 576, 0, 0, 0);
  // 10. kv_post: k_lat rmsnorm + transpose, k_pe rope
  kv_post<<<S_, B256, 0, stream>>>(kv, kvln, cs, sn, kf, klt);
  // 11. transpose kc_w (per head 128x512 -> 512x128) and vc_w (512x128 -> 128x512)
  transpose_f2b<<<dim3(512/32, 128/32, H_), Bt32, 0, stream>>>(kcw, wt, 128, 512, 65536, 65536);
  transpose_f2b<<<dim3(128/32, 512/32, H_), Bt32, 0, stream>>>(vcw, wt2, 512, 128, 65536, 65536);
  // 12. q_lat[h] = qnope[:,h,:] @ kc_w[h]  -> qf[h][:, :512]  (batched over heads)
  gemm_bt<1,0><<<dim3(4, S_/128, H_), B256, 0, stream>>>(
      qnope, wt, qf, nullptr, 1.f, S_, 512, 128, 2048, 128, 576,
      128, 65536, (long)S_ * 576);
  // 13. attention per head: scores -> softmax -> o_lat
  for (int h = 0; h < H_; ++h) {
    gemm_bt<0,0><<<dim3(S_/128, S_/128, 1), B256, 0, stream>>>(
        qf + (long)h * S_ * 576, kf, sc, nullptr, SCALE_,
        S_, S_, 576, 576, 576, S_, 0, 0, 0);
    softmax_causal<<<S_, B256, 0, stream>>>(sc, P);
    gemm_bt<1,0><<<dim3(4, S_/128, 1), B256, 0, stream>>>(
        P, klt, olat + (long)h * S_ * 512, nullptr, 1.f,
        S_, 512, S_, S_, S_, 512, 0, 0, 0);
  }
  // 14. o[:, h*128:...] = o_lat[h] @ vc_w[h] (batched over heads)
  gemm_bt<1,0><<<dim3(1, S_/128, H_), B256, 0, stream>>>(
      olat, wt2, obf, nullptr, 1.f, S_, 128, 512, 512, 512, 2048,
      (long)S_ * 512, 65536, 128);
  // 15-16. attn_out = o @ o_w
  transpose_f2b<<<dim3(D_/32, D_/32, 1), Bt32, 0, stream>>>(ow, wt, D_, D_, 0, 0);
  gemm_bt<0,0><<<dim3(D_/128, S_/128, 1), B256, 0, stream>>>(
      obf, wt, attn, nullptr, 1.f, S_, D_, D_, D_, D_, D_, 0, 0, 0);
  // 17. hidden = resid + attn; x2 = rmsnorm(hidden, ln2)
  add_rms<<<S_, B256, 0, stream>>>(hs, attn, ln2, hidden, x2);
  // 18-19. gu = x2 @ gate_up_w
  transpose_f2b<<<dim3(2 * I_ / 32, D_/32, 1), Bt32, 0, stream>>>(guw, wt, D_, 2 * I_, 0, 0);
  gemm_bt<1,0><<<dim3(2 * I_ / 128, S_/128, 1), B256, 0, stream>>>(
      x2, wt, gu, nullptr, 1.f, S_, 2 * I_, D_, D_, D_, 2 * I_, 0, 0, 0);
  // 20. mlp_in = silu(g)*u
  silu_mul<<<4096, B256, 0, stream>>>(gu, mlp);
  // 21-22. out = hidden + mlp_in @ down_w
  transpose_f2b<<<dim3(D_/32, I_/32, 1), Bt32, 0, stream>>>(dww, wt, I_, D_, 0, 0);
  gemm_bt<0,1><<<dim3(D_/128, S_/128, 1), B256, 0, stream>>>(
      mlp, wt, out, hidden, 1.f, S_, D_, I_, I_, I_, D_, 0, 0, 0);
}

// Round 2
// 1323.127 us; speedup vs baseline: 1.6089x; 1.6089x over previous
//
#include <hip/hip_runtime.h>
#include <stdint.h>

// ---------------------------------------------------------------------------
// DeepSeek-V2 decoder layer, MI355X round 2.
// R1->R2: attention batched over heads (groups of 4, blockIdx.z), causal
// triangular block-skip in scores GEMM, K-truncation in PV GEMM, bf16 scores
// with in-place softmax, vectorized silu_mul.
// ---------------------------------------------------------------------------

#define S_   2048
#define D_   2048
#define H_   16
#define QL_  1536
#define KVL_ 512
#define DN_  128
#define DR_  64
#define DV_  128
#define I_   8192
#define SCALE_ 0.07216878364870323f   // (DN+DR)^-0.5

typedef __bf16 bf16x8 __attribute__((ext_vector_type(8)));
typedef float f32x4 __attribute__((ext_vector_type(4)));

__device__ __forceinline__ unsigned short f2bf(float f) {
  unsigned int u = __builtin_bit_cast(unsigned int, f);
  u += 0x7fffu + ((u >> 16) & 1u);           // RNE
  return (unsigned short)(u >> 16);
}
__device__ __forceinline__ float bf2f(unsigned short b) {
  unsigned int u = ((unsigned int)b) << 16;
  return __builtin_bit_cast(float, u);
}

__device__ __forceinline__ float block_sum256(float v) {
  __shared__ float red[4];
  #pragma unroll
  for (int o = 32; o; o >>= 1) v += __shfl_xor(v, o);
  __syncthreads();
  if ((threadIdx.x & 63) == 0) red[threadIdx.x >> 6] = v;
  __syncthreads();
  return red[0] + red[1] + red[2] + red[3];
}
__device__ __forceinline__ float block_max256(float v) {
  __shared__ float red[4];
  #pragma unroll
  for (int o = 32; o; o >>= 1) v = fmaxf(v, __shfl_xor(v, o));
  __syncthreads();
  if ((threadIdx.x & 63) == 0) red[threadIdx.x >> 6] = v;
  __syncthreads();
  return fmaxf(fmaxf(red[0], red[1]), fmaxf(red[2], red[3]));
}

__device__ __forceinline__ void gload_lds16(const void* g, void* l) {
  void* gn = const_cast<void*>(g);
  __builtin_amdgcn_global_load_lds(
      (__attribute__((address_space(1))) void*)gn,
      (__attribute__((address_space(3))) void*)l, 16, 0, 0);
}

// ---------------------------------------------------------------------------
// Generic GEMM: C[M,N] = scale * A[M,K](bf16,lda) * Bt[N,K](bf16,ldb)^T (+R)
// 128x128 block tile, 256 threads (4 waves, each 64x64 = 4x4 mfma tiles).
// TRI: blockIdx.x linearizes the lower-triangle (by>=bx) of a 16x16 block grid.
// CK:  truncate K at m0+128 (causal PV).
// ---------------------------------------------------------------------------
template <int OUT_BF16, int ADD_RES, int TRI, int CK>
__global__ __launch_bounds__(256) void gemm_bt(
    const unsigned short* __restrict__ A, const unsigned short* __restrict__ Bt,
    void* __restrict__ C, const float* __restrict__ R, float scale,
    int M, int N, int K, int lda, int ldb, int ldc,
    long sA, long sB, long sC) {
  __shared__ unsigned short As[128 * 32];
  __shared__ unsigned short Bs[128 * 32];
  const int b = blockIdx.z;
  const unsigned short* Ab = A + (long)b * sA;
  const unsigned short* Bb = Bt + (long)b * sB;
  int bx = blockIdx.x, by = blockIdx.y;
  if (TRI) {
    const int t = blockIdx.x;
    int i = (int)((sqrtf(8.f * t + 1.f) - 1.f) * 0.5f);
    while ((i + 1) * (i + 2) / 2 <= t) ++i;
    while (i * (i + 1) / 2 > t) --i;
    by = i;
    bx = t - i * (i + 1) / 2;
  }
  const int m0 = by * 128, n0 = bx * 128;
  if (CK) K = min(K, m0 + 128);
  const int tid = threadIdx.x, w = tid >> 6, lane = tid & 63;
  const int wm = (w >> 1) * 64, wn = (w & 1) * 64;
  const int fr = lane & 15;      // m (for A) / n (for B) within 16-tile
  const int fq = lane >> 4;      // quad -> k offset = fq*8

  f32x4 acc[4][4] = {};

  for (int k0 = 0; k0 < K; k0 += 32) {
    #pragma unroll
    for (int i = 0; i < 2; ++i) {
      const int c = w * 128 + i * 64 + lane;   // 16B chunk id, 512 total
      const int row = c >> 2, q = c & 3;       // 4 chunks per 32-elem row
      gload_lds16(Ab + (long)(m0 + row) * lda + k0 + q * 8,
                  As + (w * 128 + i * 64) * 8);
      gload_lds16(Bb + (long)(n0 + row) * ldb + k0 + q * 8,
                  Bs + (w * 128 + i * 64) * 8);
    }
    __syncthreads();
    bf16x8 af[4], bfr[4];
    #pragma unroll
    for (int i = 0; i < 4; ++i)
      af[i] = *(const bf16x8*)(As + (wm + i * 16 + fr) * 32 + fq * 8);
    #pragma unroll
    for (int j = 0; j < 4; ++j)
      bfr[j] = *(const bf16x8*)(Bs + (wn + j * 16 + fr) * 32 + fq * 8);
    #pragma unroll
    for (int i = 0; i < 4; ++i)
      #pragma unroll
      for (int j = 0; j < 4; ++j)
        acc[i][j] = __builtin_amdgcn_mfma_f32_16x16x32_bf16(af[i], bfr[j],
                                                            acc[i][j], 0, 0, 0);
    __syncthreads();
  }

  const long cb = (long)b * sC;
  #pragma unroll
  for (int i = 0; i < 4; ++i) {
    const int row0 = m0 + wm + i * 16 + fq * 4;
    #pragma unroll
    for (int j = 0; j < 4; ++j) {
      const int col = n0 + wn + j * 16 + fr;
      if (col < N) {
        #pragma unroll
        for (int r = 0; r < 4; ++r) {
          const long idx = cb + (long)(row0 + r) * ldc + col;
          float v = acc[i][j][r] * scale;
          if (ADD_RES) v += R[idx];
          if (OUT_BF16) ((unsigned short*)C)[idx] = f2bf(v);
          else          ((float*)C)[idx] = v;
        }
      }
    }
  }
}

// transpose + convert: in fp32 [R,C] -> out bf16 [C,R]; R,C multiples of 32.
__global__ void transpose_f2b(const float* __restrict__ in,
                              unsigned short* __restrict__ out, int Rr, int Cc,
                              long sIn, long sOut) {
  const int b = blockIdx.z;
  in += (long)b * sIn;
  out += (long)b * sOut;
  __shared__ float t[32][33];
  const int c0 = blockIdx.x * 32, r0 = blockIdx.y * 32;
  const int tx = threadIdx.x, ty = threadIdx.y;
  #pragma unroll
  for (int i = 0; i < 4; ++i)
    t[ty + i * 8][tx] = in[(long)(r0 + ty + i * 8) * Cc + c0 + tx];
  __syncthreads();
  #pragma unroll
  for (int i = 0; i < 4; ++i)
    out[(long)(c0 + ty + i * 8) * Rr + r0 + tx] = f2bf(t[tx][ty + i * 8]);
}

// rmsnorm rows: y_bf16 = x * rsqrt(mean(x^2)+eps) * w
__global__ void rmsnorm_k(const float* __restrict__ x, const float* __restrict__ w,
                          unsigned short* __restrict__ y, int C) {
  const int row = blockIdx.x, tid = threadIdx.x;
  const float* xr = x + (long)row * C;
  float ss = 0.f;
  for (int c = tid; c < C; c += 256) { float v = xr[c]; ss += v * v; }
  ss = block_sum256(ss);
  const float rms = rsqrtf(ss / C + 1e-6f);
  for (int c = tid; c < C; c += 256)
    y[(long)row * C + c] = f2bf(xr[c] * rms * w[c]);
}

// q postprocess: split q (S,3072) into qnope bf16 (S, H*128) and roped pe into
// qf[h][s][512..575]
__global__ void q_post(const float* __restrict__ q, const float* __restrict__ cs,
                       const float* __restrict__ sn, unsigned short* __restrict__ qnope,
                       unsigned short* __restrict__ qf) {
  const int s = blockIdx.x, tid = threadIdx.x;
  const float* qr = q + (long)s * 3072;
  for (int c = tid; c < 3072; c += 256) {
    const int h = c / 192, d = c % 192;
    if (d < 128) {
      qnope[(long)s * 2048 + h * 128 + d] = f2bf(qr[c]);
    } else {
      const int j = d - 128;
      const float x = qr[c];
      const float rot = (j < 32) ? -qr[h * 192 + 128 + j + 32]
                                 :  qr[h * 192 + 128 + j - 32];
      const float v = x * cs[s * 64 + j] + rot * sn[s * 64 + j];
      qf[(long)h * (S_ * 576) + (long)s * 576 + 512 + j] = f2bf(v);
    }
  }
}

// kv postprocess: rmsnorm first 512 -> kf[:, :512] and klat^T; rope last 64.
__global__ void kv_post(const float* __restrict__ kv, const float* __restrict__ w,
                        const float* __restrict__ cs, const float* __restrict__ sn,
                        unsigned short* __restrict__ kf, unsigned short* __restrict__ klt) {
  const int s = blockIdx.x, tid = threadIdx.x;
  const float* kr = kv + (long)s * 576;
  float ss = 0.f;
  for (int c = tid; c < 512; c += 256) { float v = kr[c]; ss += v * v; }
  ss = block_sum256(ss);
  const float rms = rsqrtf(ss / 512.f + 1e-6f);
  for (int c = tid; c < 576; c += 256) {
    if (c < 512) {
      const float v = kr[c] * rms * w[c];
      const unsigned short bv = f2bf(v);
      kf[(long)s * 576 + c] = bv;
      klt[(long)c * S_ + s] = bv;
    } else {
      const int j = c - 512;
      const float x = kr[c];
      const float rot = (j < 32) ? -kr[512 + j + 32] : kr[512 + j - 32];
      kf[(long)s * 576 + c] = f2bf(x * cs[s * 64 + j] + rot * sn[s * 64 + j]);
    }
  }
}

// causal softmax IN-PLACE on bf16 scores (one head group, z = head-in-group).
// Row r: P[c] = softmax over c<=r; zeros written for c in (r, kmax) where
// kmax = 128*ceil((r+1)/128) (cols the causal PV GEMM will read).
__global__ void softmax_causal_ip(unsigned short* __restrict__ sc, long hstride) {
  const int row = blockIdx.x, tid = threadIdx.x;
  unsigned short* sr = sc + (long)blockIdx.z * hstride + (long)row * S_;
  const int n = row + 1;
  const int kmax = ((row >> 7) + 1) << 7;
  float mx = -1e30f;
  for (int c = tid; c < n; c += 256) mx = fmaxf(mx, bf2f(sr[c]));
  mx = block_max256(mx);
  float e[8];
  float sum = 0.f;
  #pragma unroll
  for (int k = 0; k < 8; ++k) {
    const int c = tid + k * 256;
    if (c < n) { e[k] = __expf(bf2f(sr[c]) - mx); sum += e[k]; }
  }
  sum = block_sum256(sum);   // internal syncthreads: all reads of sr done
  const float inv = 1.f / sum;
  #pragma unroll
  for (int k = 0; k < 8; ++k) {
    const int c = tid + k * 256;
    if (c < n) sr[c] = f2bf(e[k] * inv);
    else if (c < kmax) sr[c] = 0;
  }
}

// hidden = resid + attn (fp32 store); x2 = rmsnorm(hidden, w) bf16
__global__ void add_rms(const float* __restrict__ resid, const float* __restrict__ attn,
                        const float* __restrict__ w, float* __restrict__ hidden,
                        unsigned short* __restrict__ x2) {
  const int s = blockIdx.x, tid = threadIdx.x;
  float ss = 0.f;
  for (int c = tid; c < D_; c += 256) {
    const float v = resid[(long)s * D_ + c] + attn[(long)s * D_ + c];
    hidden[(long)s * D_ + c] = v;
    ss += v * v;
  }
  ss = block_sum256(ss);
  const float rms = rsqrtf(ss / D_ + 1e-6f);
  for (int c = tid; c < D_; c += 256) {
    const float v = resid[(long)s * D_ + c] + attn[(long)s * D_ + c];
    x2[(long)s * D_ + c] = f2bf(v * rms * w[c]);
  }
}

// mlp_in = silu(gu[:, :I]) * gu[:, I:]  — vectorized 8 bf16 per thread
__global__ void silu_mul(const unsigned short* __restrict__ gu,
                         unsigned short* __restrict__ out) {
  const long total = (long)S_ * I_ / 8;
  for (long t = (long)blockIdx.x * 256 + threadIdx.x; t < total;
       t += (long)gridDim.x * 256) {
    const long s = t >> 10, c8 = (t & 1023) * 8;   // I_/8 = 1024
    const uint4 gv = *(const uint4*)(gu + s * (2 * I_) + c8);
    const uint4 uv = *(const uint4*)(gu + s * (2 * I_) + I_ + c8);
    const unsigned int* gp = (const unsigned int*)&gv;
    const unsigned int* up = (const unsigned int*)&uv;
    uint4 ov;
    unsigned int* op = (unsigned int*)&ov;
    #pragma unroll
    for (int k = 0; k < 4; ++k) {
      const float g0 = bf2f((unsigned short)(gp[k] & 0xffff));
      const float g1 = bf2f((unsigned short)(gp[k] >> 16));
      const float u0 = bf2f((unsigned short)(up[k] & 0xffff));
      const float u1 = bf2f((unsigned short)(up[k] >> 16));
      const float r0 = g0 / (1.f + __expf(-g0)) * u0;
      const float r1 = g1 / (1.f + __expf(-g1)) * u1;
      op[k] = (unsigned int)f2bf(r0) | ((unsigned int)f2bf(r1) << 16);
    }
    *(uint4*)(out + t * 8) = ov;
  }
}

// ---------------------------------------------------------------------------
extern "C" void kernel_launch(void* const* d_in, const int* in_sizes, int n_in,
                              void* d_out, int out_size, void* d_ws, size_t ws_size,
                              hipStream_t stream) {
  const float* hs   = (const float*)d_in[0];
  const float* cs   = (const float*)d_in[1];
  const float* sn   = (const float*)d_in[2];
  const float* ln1  = (const float*)d_in[3];
  const float* qaw  = (const float*)d_in[4];
  const float* qaln = (const float*)d_in[5];
  const float* qbw  = (const float*)d_in[6];
  const float* kvaw = (const float*)d_in[7];
  const float* kvln = (const float*)d_in[8];
  const float* kcw  = (const float*)d_in[9];
  const float* vcw  = (const float*)d_in[10];
  const float* ow   = (const float*)d_in[11];
  const float* ln2  = (const float*)d_in[12];
  const float* guw  = (const float*)d_in[13];
  const float* dww  = (const float*)d_in[14];
  float* out = (float*)d_out;
  char* ws = (char*)d_ws;

  // ---- workspace layout (bytes); high-water 192937984 (< R1's 195035136) ---
  // pre-attention phase
  unsigned short* hbf   = (unsigned short*)(ws + 0);           // S*D bf16 8MB
  float*          qa    = (float*)(ws + 8388608);              // S*QL f32 12MB
  unsigned short* qan   = (unsigned short*)(ws + 20971520);    // S*QL bf16 6MB
  float*          q     = (float*)(ws + 27262976);             // S*3072 f32 24MB
  unsigned short* qnope = (unsigned short*)(ws + 52428800);    // S*2048 bf16 8MB
  unsigned short* qf    = (unsigned short*)(ws + 60817408);    // H*S*576 bf16 36MB
  float*          kv    = (float*)(ws + 98566144);             // S*576 f32
  unsigned short* kf    = (unsigned short*)(ws + 103284736);   // S*576 bf16
  unsigned short* klt   = (unsigned short*)(ws + 105644032);   // 512*S bf16 2MB
  unsigned short* wt2   = (unsigned short*)(ws + 123731968);   // vc^T 2MB
  unsigned short* wt    = (unsigned short*)(ws + 125829120);   // weight scratch 67MB
  // attention phase (aliases dead pre-attention buffers)
  unsigned short* sc    = (unsigned short*)(ws + 0);           // 4 heads bf16 S*S 32MB
  unsigned short* olat  = (unsigned short*)(ws + 125829120);   // H*S*512 bf16 33.5MB (kc^T dead)
  // post-attention phase
  unsigned short* obf   = (unsigned short*)(ws + 0);           // S*2048 bf16 8MB
  float*          attn  = (float*)(ws + 8388608);              // S*D f32 16MB
  float*          hidden= (float*)(ws + 33554432);             // S*D f32 16MB
  unsigned short* x2    = (unsigned short*)(ws + 50331648);    // S*D bf16 8MB
  unsigned short* gu    = (unsigned short*)(ws + 58720256);    // S*2I bf16 67MB (ends 125829120)
  unsigned short* mlp   = (unsigned short*)(ws + 0);           // S*I bf16 33.5MB
  unsigned short* wtB   = (unsigned short*)(ws + 125829120);   // o_w^T / guw^T / dww^T (olat dead by then)

  const dim3 B256(256), Bt32(32, 8);

  // 1. h = rmsnorm(hidden_states, ln1)
  rmsnorm_k<<<S_, B256, 0, stream>>>(hs, ln1, hbf, D_);
  // 2-3. q_a = h @ q_a_w
  transpose_f2b<<<dim3(QL_/32, D_/32, 1), Bt32, 0, stream>>>(qaw, wt, D_, QL_, 0, 0);
  gemm_bt<0,0,0,0><<<dim3(QL_/128, S_/128, 1), B256, 0, stream>>>(
      hbf, wt, qa, nullptr, 1.f, S_, QL_, D_, D_, D_, QL_, 0, 0, 0);
  // 4. q_a_norm
  rmsnorm_k<<<S_, B256, 0, stream>>>(qa, qaln, qan, QL_);
  // 5-6. q = qan @ q_b_w
  transpose_f2b<<<dim3(3072/32, QL_/32, 1), Bt32, 0, stream>>>(qbw, wt, QL_, 3072, 0, 0);
  gemm_bt<0,0,0,0><<<dim3(3072/128, S_/128, 1), B256, 0, stream>>>(
      qan, wt, q, nullptr, 1.f, S_, 3072, QL_, QL_, QL_, 3072, 0, 0, 0);
  // 7. split q -> qnope bf16, rope(q_pe) -> qf[...,512:]
  q_post<<<S_, B256, 0, stream>>>(q, cs, sn, qnope, qf);
  // 8-9. kv = h @ kv_a_w
  transpose_f2b<<<dim3(576/32, D_/32, 1), Bt32, 0, stream>>>(kvaw, wt, D_, 576, 0, 0);
  gemm_bt<0,0,0,0><<<dim3(5, S_/128, 1), B256, 0, stream>>>(
      hbf, wt, kv, nullptr, 1.f, S_, 576, D_, D_, D_, 576, 0, 0, 0);
  // 10. kv_post: k_lat rmsnorm + transpose, k_pe rope
  kv_post<<<S_, B256, 0, stream>>>(kv, kvln, cs, sn, kf, klt);
  // 11. transpose kc_w (per head 128x512 -> 512x128) and vc_w (512x128 -> 128x512)
  transpose_f2b<<<dim3(512/32, 128/32, H_), Bt32, 0, stream>>>(kcw, wt, 128, 512, 65536, 65536);
  transpose_f2b<<<dim3(128/32, 512/32, H_), Bt32, 0, stream>>>(vcw, wt2, 512, 128, 65536, 65536);
  // 12. q_lat[h] = qnope[:,h,:] @ kc_w[h]  -> qf[h][:, :512]  (batched over heads)
  gemm_bt<1,0,0,0><<<dim3(4, S_/128, H_), B256, 0, stream>>>(
      qnope, wt, qf, nullptr, 1.f, S_, 512, 128, 2048, 128, 576,
      128, 65536, (long)S_ * 576);
  // 13. attention, 4 heads per group: tri-scores(bf16) -> in-place softmax -> causal PV
  for (int g = 0; g < 4; ++g) {
    const unsigned short* qfg = qf + (long)g * 4 * S_ * 576;
    // scores: lower-triangle blocks only (136 of 256), bf16 out, scaled
    gemm_bt<1,0,1,0><<<dim3(136, 1, 4), B256, 0, stream>>>(
        qfg, kf, sc, nullptr, SCALE_, S_, S_, 576, 576, 576, S_,
        (long)S_ * 576, 0, (long)S_ * S_);
    softmax_causal_ip<<<dim3(S_, 1, 4), B256, 0, stream>>>(sc, (long)S_ * S_);
    // o_lat = P @ k_lat : K truncated at m0+128 (causal)
    gemm_bt<1,0,0,1><<<dim3(4, 16, 4), B256, 0, stream>>>(
        sc, klt, olat + (long)g * 4 * S_ * 512, nullptr, 1.f,
        S_, 512, S_, S_, S_, 512, (long)S_ * S_, 0, (long)S_ * 512);
  }
  // 14. o[:, h*128:...] = o_lat[h] @ vc_w[h] (batched over heads)
  gemm_bt<1,0,0,0><<<dim3(1, S_/128, H_), B256, 0, stream>>>(
      olat, wt2, obf, nullptr, 1.f, S_, 128, 512, 512, 512, 2048,
      (long)S_ * 512, 65536, 128);
  // 15-16. attn_out = o @ o_w
  transpose_f2b<<<dim3(D_/32, D_/32, 1), Bt32, 0, stream>>>(ow, wtB, D_, D_, 0, 0);
  gemm_bt<0,0,0,0><<<dim3(D_/128, S_/128, 1), B256, 0, stream>>>(
      obf, wtB, attn, nullptr, 1.f, S_, D_, D_, D_, D_, D_, 0, 0, 0);
  // 17. hidden = resid + attn; x2 = rmsnorm(hidden, ln2)
  add_rms<<<S_, B256, 0, stream>>>(hs, attn, ln2, hidden, x2);
  // 18-19. gu = x2 @ gate_up_w
  transpose_f2b<<<dim3(2 * I_ / 32, D_/32, 1), Bt32, 0, stream>>>(guw, wtB, D_, 2 * I_, 0, 0);
  gemm_bt<1,0,0,0><<<dim3(2 * I_ / 128, S_/128, 1), B256, 0, stream>>>(
      x2, wtB, gu, nullptr, 1.f, S_, 2 * I_, D_, D_, D_, 2 * I_, 0, 0, 0);
  // 20. mlp_in = silu(g)*u
  silu_mul<<<2048, B256, 0, stream>>>(gu, mlp);
  // 21-22. out = hidden + mlp_in @ down_w
  transpose_f2b<<<dim3(D_/32, I_/32, 1), Bt32, 0, stream>>>(dww, wtB, I_, D_, 0, 0);
  gemm_bt<0,1,0,0><<<dim3(D_/128, S_/128, 1), B256, 0, stream>>>(
      mlp, wtB, out, hidden, 1.f, S_, D_, I_, I_, I_, D_, 0, 0, 0);
}

// Round 3
// 1080.508 us; speedup vs baseline: 1.9701x; 1.2245x over previous
//
#include <hip/hip_runtime.h>
#include <stdint.h>

// ---------------------------------------------------------------------------
// DeepSeek-V2 decoder layer, MI355X round 3.
// R2->R3: BK=64 GEMM with XOR-swizzled LDS staging (kills 8-way bank conflict
// on ds_read_b128 fragment loads), silu fused into gate_up epilogue via
// interleaved weight transpose, residual-add fused into o_w GEMM,
// attention in 2 groups of 8 heads. 27 dispatches total.
// ---------------------------------------------------------------------------

#define S_   2048
#define D_   2048
#define H_   16
#define QL_  1536
#define KVL_ 512
#define DN_  128
#define DR_  64
#define DV_  128
#define I_   8192
#define SCALE_ 0.07216878364870323f   // (DN+DR)^-0.5

typedef __bf16 bf16x8 __attribute__((ext_vector_type(8)));
typedef float f32x4 __attribute__((ext_vector_type(4)));

__device__ __forceinline__ unsigned short f2bf(float f) {
  unsigned int u = __builtin_bit_cast(unsigned int, f);
  u += 0x7fffu + ((u >> 16) & 1u);           // RNE
  return (unsigned short)(u >> 16);
}
__device__ __forceinline__ float bf2f(unsigned short b) {
  unsigned int u = ((unsigned int)b) << 16;
  return __builtin_bit_cast(float, u);
}

__device__ __forceinline__ float block_sum256(float v) {
  __shared__ float red[4];
  #pragma unroll
  for (int o = 32; o; o >>= 1) v += __shfl_xor(v, o);
  __syncthreads();
  if ((threadIdx.x & 63) == 0) red[threadIdx.x >> 6] = v;
  __syncthreads();
  return red[0] + red[1] + red[2] + red[3];
}
__device__ __forceinline__ float block_max256(float v) {
  __shared__ float red[4];
  #pragma unroll
  for (int o = 32; o; o >>= 1) v = fmaxf(v, __shfl_xor(v, o));
  __syncthreads();
  if ((threadIdx.x & 63) == 0) red[threadIdx.x >> 6] = v;
  __syncthreads();
  return fmaxf(fmaxf(red[0], red[1]), fmaxf(red[2], red[3]));
}

__device__ __forceinline__ void gload_lds16(const void* g, void* l) {
  void* gn = const_cast<void*>(g);
  __builtin_amdgcn_global_load_lds(
      (__attribute__((address_space(1))) void*)gn,
      (__attribute__((address_space(3))) void*)l, 16, 0, 0);
}

// ---------------------------------------------------------------------------
// GEMM: C[M,N] = scale * A[M,K](bf16,lda) * Bt[N,K](bf16,ldb)^T (+R)
// 128x128 tile, BK=64, 256 threads (4 waves, 64x64 each, 4x4 mfma tiles).
// LDS rows are 128B (all 32 banks); chunk c of row r stored at c^(r&7)
// (swizzle applied on the GLOBAL source address; LDS dest stays contiguous
// as required by global_load_lds). Fragment ds_read_b128 is then 2-way
// bank-aliased only (free per m136).
// OUT: 0=f32, 1=bf16, 2=silu-pair bf16 (even col=gate, odd=up; writes N/2).
// TRI: blockIdx.x linearizes lower-triangle of 16x16 grid. CK: K=min(K,m0+128).
// ---------------------------------------------------------------------------
template <int OUT, int ADD_RES, int TRI, int CK>
__global__ __launch_bounds__(256) void gemm_bt(
    const unsigned short* __restrict__ A, const unsigned short* __restrict__ Bt,
    void* __restrict__ C, const float* __restrict__ R, float scale,
    int M, int N, int K, int lda, int ldb, int ldc,
    long sA, long sB, long sC) {
  __shared__ unsigned short As[128 * 64];
  __shared__ unsigned short Bs[128 * 64];
  const int b = blockIdx.z;
  int bx = blockIdx.x, by = blockIdx.y;
  if (TRI) {
    const int t = blockIdx.x;
    int i = (int)((sqrtf(8.f * t + 1.f) - 1.f) * 0.5f);
    while ((i + 1) * (i + 2) / 2 <= t) ++i;
    while (i * (i + 1) / 2 > t) --i;
    by = i;
    bx = t - i * (i + 1) / 2;
  }
  const int m0 = by * 128, n0 = bx * 128;
  if (CK) K = min(K, m0 + 128);
  const int tid = threadIdx.x, w = tid >> 6, lane = tid & 63;
  const int wm = (w >> 1) * 64, wn = (w & 1) * 64;
  const int fr = lane & 15;      // m (A) / n (B) within 16-tile
  const int fq = lane >> 4;      // quad
  // staging: lane covers row (base + lane/8), chunk position lane%8 in LDS;
  // source global chunk = (lane%8) ^ (lane/8)  [row&7 == lane/8].
  const int sr = lane >> 3;
  const int sch = (lane & 7) ^ sr;
  const unsigned short* Ab = A + (long)b * sA;
  const unsigned short* Bb = Bt + (long)b * sB;
  long aOff[4], bOff[4];
  #pragma unroll
  for (int i = 0; i < 4; ++i) {
    const int row = w * 32 + i * 8 + sr;
    aOff[i] = (long)(m0 + row) * lda + sch * 8;
    bOff[i] = (long)(n0 + row) * ldb + sch * 8;
  }
  // fragment chunk index (same for A and B rows: row&7 == fr&7)
  const int ca0 = fq ^ (fr & 7);
  const int ca1 = (4 + fq) ^ (fr & 7);

  f32x4 acc[4][4] = {};

  for (int k0 = 0; k0 < K; k0 += 64) {
    #pragma unroll
    for (int i = 0; i < 4; ++i) {
      gload_lds16(Ab + aOff[i] + k0, As + (w * 32 + i * 8) * 64);
      gload_lds16(Bb + bOff[i] + k0, Bs + (w * 32 + i * 8) * 64);
    }
    __syncthreads();
    #pragma unroll
    for (int s = 0; s < 2; ++s) {
      const int cc = s ? ca1 : ca0;
      bf16x8 af[4], bf[4];
      #pragma unroll
      for (int i = 0; i < 4; ++i)
        af[i] = *(const bf16x8*)(As + (wm + i * 16 + fr) * 64 + cc * 8);
      #pragma unroll
      for (int j = 0; j < 4; ++j)
        bf[j] = *(const bf16x8*)(Bs + (wn + j * 16 + fr) * 64 + cc * 8);
      #pragma unroll
      for (int i = 0; i < 4; ++i)
        #pragma unroll
        for (int j = 0; j < 4; ++j)
          acc[i][j] = __builtin_amdgcn_mfma_f32_16x16x32_bf16(af[i], bf[j],
                                                              acc[i][j], 0, 0, 0);
    }
    __syncthreads();
  }

  const long cb = (long)b * sC;
  #pragma unroll
  for (int i = 0; i < 4; ++i) {
    const int row0 = m0 + wm + i * 16 + fq * 4;
    #pragma unroll
    for (int j = 0; j < 4; ++j) {
      const int col = n0 + wn + j * 16 + fr;
      #pragma unroll
      for (int r = 0; r < 4; ++r) {
        float v = acc[i][j][r] * scale;
        if (OUT == 2) {
          const float o = __shfl_xor(v, 1);   // partner col (gate<->up)
          const float res = v / (1.f + __expf(-v)) * o;  // valid on even lanes
          if (((fr & 1) == 0) && col < N)
            ((unsigned short*)C)[cb + (long)(row0 + r) * ldc + (col >> 1)] =
                f2bf(res);
        } else {
          if (col < N) {
            const long idx = cb + (long)(row0 + r) * ldc + col;
            float vv = v;
            if (ADD_RES) vv += R[idx];
            if (OUT == 1) ((unsigned short*)C)[idx] = f2bf(vv);
            else          ((float*)C)[idx] = vv;
          }
        }
      }
    }
  }
}

// transpose + convert: in fp32 [R,C] -> out bf16 [C,R]; R,C multiples of 32.
__global__ void transpose_f2b(const float* __restrict__ in,
                              unsigned short* __restrict__ out, int Rr, int Cc,
                              long sIn, long sOut) {
  const int b = blockIdx.z;
  in += (long)b * sIn;
  out += (long)b * sOut;
  __shared__ float t[32][33];
  const int c0 = blockIdx.x * 32, r0 = blockIdx.y * 32;
  const int tx = threadIdx.x, ty = threadIdx.y;
  #pragma unroll
  for (int i = 0; i < 4; ++i)
    t[ty + i * 8][tx] = in[(long)(r0 + ty + i * 8) * Cc + c0 + tx];
  __syncthreads();
  #pragma unroll
  for (int i = 0; i < 4; ++i)
    out[(long)(c0 + ty + i * 8) * Rr + r0 + tx] = f2bf(t[tx][ty + i * 8]);
}

// interleaved transpose for gate_up: col c of [D,2I] -> row 2*(c%I)+(c/I).
__global__ void transpose_f2b_ilv(const float* __restrict__ in,
                                  unsigned short* __restrict__ out) {
  __shared__ float t[32][33];
  const int c0 = blockIdx.x * 32, r0 = blockIdx.y * 32;
  const int tx = threadIdx.x, ty = threadIdx.y;
  #pragma unroll
  for (int i = 0; i < 4; ++i)
    t[ty + i * 8][tx] = in[(long)(r0 + ty + i * 8) * (2 * I_) + c0 + tx];
  __syncthreads();
  #pragma unroll
  for (int i = 0; i < 4; ++i) {
    const int c = c0 + ty + i * 8;
    const int n = ((c & (I_ - 1)) << 1) | (c >> 13);
    out[(long)n * D_ + r0 + tx] = f2bf(t[tx][ty + i * 8]);
  }
}

// rmsnorm rows: y_bf16 = x * rsqrt(mean(x^2)+eps) * w
__global__ void rmsnorm_k(const float* __restrict__ x, const float* __restrict__ w,
                          unsigned short* __restrict__ y, int C) {
  const int row = blockIdx.x, tid = threadIdx.x;
  const float* xr = x + (long)row * C;
  float ss = 0.f;
  for (int c = tid; c < C; c += 256) { float v = xr[c]; ss += v * v; }
  ss = block_sum256(ss);
  const float rms = rsqrtf(ss / C + 1e-6f);
  for (int c = tid; c < C; c += 256)
    y[(long)row * C + c] = f2bf(xr[c] * rms * w[c]);
}

// q postprocess: split q (S,3072) into qnope bf16 (S,H*128) and roped pe into
// qf[h][s][512..575]
__global__ void q_post(const float* __restrict__ q, const float* __restrict__ cs,
                       const float* __restrict__ sn, unsigned short* __restrict__ qnope,
                       unsigned short* __restrict__ qf) {
  const int s = blockIdx.x, tid = threadIdx.x;
  const float* qr = q + (long)s * 3072;
  for (int c = tid; c < 3072; c += 256) {
    const int h = c / 192, d = c % 192;
    if (d < 128) {
      qnope[(long)s * 2048 + h * 128 + d] = f2bf(qr[c]);
    } else {
      const int j = d - 128;
      const float x = qr[c];
      const float rot = (j < 32) ? -qr[h * 192 + 128 + j + 32]
                                 :  qr[h * 192 + 128 + j - 32];
      const float v = x * cs[s * 64 + j] + rot * sn[s * 64 + j];
      qf[(long)h * (S_ * 576) + (long)s * 576 + 512 + j] = f2bf(v);
    }
  }
}

// kv postprocess: rmsnorm first 512 -> kf[:, :512] and klat^T; rope last 64.
__global__ void kv_post(const float* __restrict__ kv, const float* __restrict__ w,
                        const float* __restrict__ cs, const float* __restrict__ sn,
                        unsigned short* __restrict__ kf, unsigned short* __restrict__ klt) {
  const int s = blockIdx.x, tid = threadIdx.x;
  const float* kr = kv + (long)s * 576;
  float ss = 0.f;
  for (int c = tid; c < 512; c += 256) { float v = kr[c]; ss += v * v; }
  ss = block_sum256(ss);
  const float rms = rsqrtf(ss / 512.f + 1e-6f);
  for (int c = tid; c < 576; c += 256) {
    if (c < 512) {
      const float v = kr[c] * rms * w[c];
      const unsigned short bv = f2bf(v);
      kf[(long)s * 576 + c] = bv;
      klt[(long)c * S_ + s] = bv;
    } else {
      const int j = c - 512;
      const float x = kr[c];
      const float rot = (j < 32) ? -kr[512 + j + 32] : kr[512 + j - 32];
      kf[(long)s * 576 + c] = f2bf(x * cs[s * 64 + j] + rot * sn[s * 64 + j]);
    }
  }
}

// causal softmax IN-PLACE on bf16 scores. Row r: softmax over c<=r; zeros for
// c in (r, kmax), kmax = 128*ceil((r+1)/128) (cols the causal PV GEMM reads).
__global__ void softmax_causal_ip(unsigned short* __restrict__ sc, long hstride) {
  const int row = blockIdx.x, tid = threadIdx.x;
  unsigned short* sr = sc + (long)blockIdx.z * hstride + (long)row * S_;
  const int n = row + 1;
  const int kmax = ((row >> 7) + 1) << 7;
  float mx = -1e30f;
  for (int c = tid; c < n; c += 256) mx = fmaxf(mx, bf2f(sr[c]));
  mx = block_max256(mx);
  float e[8];
  float sum = 0.f;
  #pragma unroll
  for (int k = 0; k < 8; ++k) {
    const int c = tid + k * 256;
    if (c < n) { e[k] = __expf(bf2f(sr[c]) - mx); sum += e[k]; }
  }
  sum = block_sum256(sum);   // internal syncthreads: all reads of sr done
  const float inv = 1.f / sum;
  #pragma unroll
  for (int k = 0; k < 8; ++k) {
    const int c = tid + k * 256;
    if (c < n) sr[c] = f2bf(e[k] * inv);
    else if (c < kmax) sr[c] = 0;
  }
}

// ---------------------------------------------------------------------------
extern "C" void kernel_launch(void* const* d_in, const int* in_sizes, int n_in,
                              void* d_out, int out_size, void* d_ws, size_t ws_size,
                              hipStream_t stream) {
  const float* hs   = (const float*)d_in[0];
  const float* cs   = (const float*)d_in[1];
  const float* sn   = (const float*)d_in[2];
  const float* ln1  = (const float*)d_in[3];
  const float* qaw  = (const float*)d_in[4];
  const float* qaln = (const float*)d_in[5];
  const float* qbw  = (const float*)d_in[6];
  const float* kvaw = (const float*)d_in[7];
  const float* kvln = (const float*)d_in[8];
  const float* kcw  = (const float*)d_in[9];
  const float* vcw  = (const float*)d_in[10];
  const float* ow   = (const float*)d_in[11];
  const float* ln2  = (const float*)d_in[12];
  const float* guw  = (const float*)d_in[13];
  const float* dww  = (const float*)d_in[14];
  float* out = (float*)d_out;
  char* ws = (char*)d_ws;

  // ---- workspace layout (bytes); high-water 183697408 ----------------------
  // pre-attention (dead before scores are written)
  unsigned short* hbf   = (unsigned short*)(ws + 0);           // S*D bf16 8MB
  float*          qa    = (float*)(ws + 8388608);              // S*QL f32
  unsigned short* qan   = (unsigned short*)(ws + 20971520);    // S*QL bf16
  float*          q     = (float*)(ws + 27262976);             // S*3072 f32
  unsigned short* qnope = (unsigned short*)(ws + 52428800);    // S*2048 bf16 ends 60817408
  // attention
  unsigned short* sc    = (unsigned short*)(ws + 0);           // 8 heads S*S bf16 = 64MB
  unsigned short* qf    = (unsigned short*)(ws + 67108864);    // H*S*576 bf16 ends 104857600
  float*          kv    = (float*)(ws + 104857600);            // S*576 f32
  unsigned short* kf    = (unsigned short*)(ws + 109576192);   // S*576 bf16
  unsigned short* klt   = (unsigned short*)(ws + 111935488);   // 512*S bf16
  unsigned short* wt2   = (unsigned short*)(ws + 114032640);   // vc^T 2MB
  unsigned short* wt    = (unsigned short*)(ws + 116129792);   // weight scratch (<=67MB, ends 183697408)
  unsigned short* olat  = (unsigned short*)(ws + 116129792);   // H*S*512 bf16 (aliases wt; kc^T dead first,
                                                               // wt reused only after olat consumed)
  // post-attention
  unsigned short* obf   = (unsigned short*)(ws + 0);           // S*2048 bf16 8MB
  float*          hidden= (float*)(ws + 8388608);              // S*D f32 ends 25165824
  unsigned short* x2    = (unsigned short*)(ws + 25165824);    // S*D bf16 ends 33554432
  unsigned short* mlp   = (unsigned short*)(ws + 33554432);    // S*I bf16 ends 67108864

  const dim3 B256(256), Bt32(32, 8);

  // 1. h = rmsnorm(hidden_states, ln1)
  rmsnorm_k<<<S_, B256, 0, stream>>>(hs, ln1, hbf, D_);
  // 2-3. q_a = h @ q_a_w
  transpose_f2b<<<dim3(QL_/32, D_/32, 1), Bt32, 0, stream>>>(qaw, wt, D_, QL_, 0, 0);
  gemm_bt<0,0,0,0><<<dim3(QL_/128, S_/128, 1), B256, 0, stream>>>(
      hbf, wt, qa, nullptr, 1.f, S_, QL_, D_, D_, D_, QL_, 0, 0, 0);
  // 4. q_a_norm
  rmsnorm_k<<<S_, B256, 0, stream>>>(qa, qaln, qan, QL_);
  // 5-6. q = qan @ q_b_w
  transpose_f2b<<<dim3(3072/32, QL_/32, 1), Bt32, 0, stream>>>(qbw, wt, QL_, 3072, 0, 0);
  gemm_bt<0,0,0,0><<<dim3(3072/128, S_/128, 1), B256, 0, stream>>>(
      qan, wt, q, nullptr, 1.f, S_, 3072, QL_, QL_, QL_, 3072, 0, 0, 0);
  // 7. split q -> qnope bf16, rope(q_pe) -> qf[...,512:]
  q_post<<<S_, B256, 0, stream>>>(q, cs, sn, qnope, qf);
  // 8-9. kv = h @ kv_a_w
  transpose_f2b<<<dim3(576/32, D_/32, 1), Bt32, 0, stream>>>(kvaw, wt, D_, 576, 0, 0);
  gemm_bt<0,0,0,0><<<dim3(5, S_/128, 1), B256, 0, stream>>>(
      hbf, wt, kv, nullptr, 1.f, S_, 576, D_, D_, D_, 576, 0, 0, 0);
  // 10. kv_post: k_lat rmsnorm + transpose, k_pe rope
  kv_post<<<S_, B256, 0, stream>>>(kv, kvln, cs, sn, kf, klt);
  // 11-12. transpose kc_w (128x512 -> 512x128 per head) and vc_w (512x128 -> 128x512)
  transpose_f2b<<<dim3(512/32, 128/32, H_), Bt32, 0, stream>>>(kcw, wt, 128, 512, 65536, 65536);
  transpose_f2b<<<dim3(128/32, 512/32, H_), Bt32, 0, stream>>>(vcw, wt2, 512, 128, 65536, 65536);
  // 13. q_lat[h] = qnope[:,h,:] @ kc_w[h] -> qf[h][:, :512]
  gemm_bt<1,0,0,0><<<dim3(4, S_/128, H_), B256, 0, stream>>>(
      qnope, wt, qf, nullptr, 1.f, S_, 512, 128, 2048, 128, 576,
      128, 65536, (long)S_ * 576);
  // 14-19. attention, 2 groups of 8 heads
  for (int g = 0; g < 2; ++g) {
    const unsigned short* qfg = qf + (long)g * 8 * S_ * 576;
    gemm_bt<1,0,1,0><<<dim3(136, 1, 8), B256, 0, stream>>>(
        qfg, kf, sc, nullptr, SCALE_, S_, S_, 576, 576, 576, S_,
        (long)S_ * 576, 0, (long)S_ * S_);
    softmax_causal_ip<<<dim3(S_, 1, 8), B256, 0, stream>>>(sc, (long)S_ * S_);
    gemm_bt<1,0,0,1><<<dim3(4, 16, 8), B256, 0, stream>>>(
        sc, klt, olat + (long)g * 8 * S_ * 512, nullptr, 1.f,
        S_, 512, S_, S_, S_, 512, (long)S_ * S_, 0, (long)S_ * 512);
  }
  // 20. o[:, h*128:...] = o_lat[h] @ vc_w[h]
  gemm_bt<1,0,0,0><<<dim3(1, S_/128, H_), B256, 0, stream>>>(
      olat, wt2, obf, nullptr, 1.f, S_, 128, 512, 512, 512, 2048,
      (long)S_ * 512, 65536, 128);
  // 21-22. hidden = hs + o @ o_w   (residual fused into GEMM epilogue)
  transpose_f2b<<<dim3(D_/32, D_/32, 1), Bt32, 0, stream>>>(ow, wt, D_, D_, 0, 0);
  gemm_bt<0,1,0,0><<<dim3(D_/128, S_/128, 1), B256, 0, stream>>>(
      obf, wt, hidden, hs, 1.f, S_, D_, D_, D_, D_, D_, 0, 0, 0);
  // 23. x2 = rmsnorm(hidden, ln2)
  rmsnorm_k<<<S_, B256, 0, stream>>>(hidden, ln2, x2, D_);
  // 24-25. mlp = silu(x2@gate) * (x2@up)  (silu fused in epilogue, interleaved cols)
  transpose_f2b_ilv<<<dim3(2 * I_ / 32, D_/32, 1), Bt32, 0, stream>>>(guw, wt);
  gemm_bt<2,0,0,0><<<dim3(2 * I_ / 128, S_/128, 1), B256, 0, stream>>>(
      x2, wt, mlp, nullptr, 1.f, S_, 2 * I_, D_, D_, D_, I_, 0, 0, 0);
  // 26-27. out = hidden + mlp @ down_w
  transpose_f2b<<<dim3(D_/32, I_/32, 1), Bt32, 0, stream>>>(dww, wt, I_, D_, 0, 0);
  gemm_bt<0,1,0,0><<<dim3(D_/128, S_/128, 1), B256, 0, stream>>>(
      mlp, wt, out, hidden, 1.f, S_, D_, I_, I_, I_, D_, 0, 0, 0);
}